// Round 9
// baseline (93.848 us; speedup 1.0000x reference)
//
#include <hip/hip_runtime.h>
#include <hip/hip_fp16.h>

#define DIM 64

// ---------- pass 1: compress x (f32) -> xh (fp16) in workspace ----------
__global__ __launch_bounds__(256) void cvt_half_kernel(
    const float* __restrict__ x, __half* __restrict__ xh, int n4)
{
    int i = blockIdx.x * blockDim.x + threadIdx.x;
    const int stride = gridDim.x * blockDim.x;
    for (; i < n4; i += stride) {
        const float4 v = ((const float4*)x)[i];
        __half2 h0 = __floats2half2_rn(v.x, v.y);
        __half2 h1 = __floats2half2_rn(v.z, v.w);
        uint2 u;
        u.x = *(const unsigned int*)&h0;
        u.y = *(const unsigned int*)&h1;
        ((uint2*)xh)[i] = u;
    }
}

// ---------- pass 2: per-row sort of (indices, values) by index ----------
// One wave per row; 64-edge chunks sorted independently with an in-register
// bitonic sort. key = (index<<6)|lane (index<2^17 so fits int); payload value
// recovered via shfl from the original lane. Sorted rows turn the random
// gather into an ascending sweep through node space.
__global__ __launch_bounds__(256) void sort_rows_kernel(
    const int*   __restrict__ indptr,
    const int*   __restrict__ indices,
    const float* __restrict__ values,
    int*         __restrict__ sidx,
    float*       __restrict__ sval,
    int n_nodes)
{
    const int wave = (int)((blockIdx.x * blockDim.x + threadIdx.x) >> 6);
    const int lane = (int)(threadIdx.x & 63);
    if (wave >= n_nodes) return;
    const int s = indptr[wave];
    const int e = indptr[wave + 1];

    for (int base = s; base < e; base += 64) {
        const int m = e - base < 64 ? e - base : 64;
        int key = 0x7fffffff;
        float v = 0.f;
        if (lane < m) {
            key = (indices[base + lane] << 6) | lane;
            v   = values[base + lane];
        }
        // bitonic sort, ascending, over the 64-lane wave
#pragma unroll
        for (int k = 2; k <= 64; k <<= 1) {
#pragma unroll
            for (int j = k >> 1; j >= 1; j >>= 1) {
                const int other = __shfl_xor(key, j);
                const bool up    = ((lane & k) == 0);
                const bool lower = ((lane & j) == 0);
                const int mn = key < other ? key : other;
                const int mx = key < other ? other : key;
                key = (up == lower) ? mn : mx;
            }
        }
        const int   src = key & 63;
        const float sv  = __shfl(v, src);
        if (lane < m) {
            sidx[base + lane] = key >> 6;
            sval[base + lane] = sv;
        }
    }
}

// ---------- pass 3: CSR SpMM over fp16 x, sorted edges, balanced waves ----
// Co-resident grid (2048 blocks = 8192 waves). Wave w handles rows
// [lb(E*w/W), lb(E*(w+1)/W)) -- equal ~E/W edges per wave, so all waves sweep
// their sorted edge lists in phase: gathers cluster in a sliding node-ID band
// that fits per-XCD L2. Hot loop: 8 groups x 8 lanes, 16-edge clamped tiles,
// 1 cache line per edge.
__global__ __launch_bounds__(256, 8) void spmm_half_sorted_kernel(
    const __half* __restrict__ xh,
    const int*   __restrict__ indptr,
    const int*   __restrict__ sidx,
    const float* __restrict__ sval,
    float*       __restrict__ out,
    int n_nodes, int n_edges, int n_waves)
{
    const int wave = (int)((blockIdx.x * blockDim.x + threadIdx.x) >> 6);
    const int lane = (int)(threadIdx.x & 63);
    if (wave >= n_waves) return;
    const int g = lane >> 3;        // edge slot 0..7
    const int t = lane & 7;         // column octet

    // first row with indptr[r] >= target
    const long long T0 = (long long)n_edges * wave / n_waves;
    const long long T1 = (long long)n_edges * (wave + 1) / n_waves;
    int lo = 0, hi = n_nodes;
    while (lo < hi) { int mid = (lo + hi) >> 1; if ((long long)indptr[mid] < T0) lo = mid + 1; else hi = mid; }
    const int r0 = lo;
    int r1;
    if (wave == n_waves - 1) { r1 = n_nodes; }
    else {
        lo = r0; hi = n_nodes;
        while (lo < hi) { int mid = (lo + hi) >> 1; if ((long long)indptr[mid] < T1) lo = mid + 1; else hi = mid; }
        r1 = lo;
    }

    for (int row = r0; row < r1; ++row) {
        const int start = indptr[row];
        const int end   = indptr[row + 1];

        float a[8] = {0.f,0.f,0.f,0.f,0.f,0.f,0.f,0.f};

        if (start < end) {
            const int last = end - 1;
            for (int k = start; k < end; k += 16) {
                const int e0 = k + g;
                const int e1 = k + 8 + g;
                const int i0 = (e0 <= last) ? e0 : last;
                const int i1 = (e1 <= last) ? e1 : last;
                const int c0 = sidx[i0];
                const int c1 = sidx[i1];
                const float w0 = (e0 <= last) ? sval[i0] : 0.0f;
                const float w1 = (e1 <= last) ? sval[i1] : 0.0f;

                const uint4 p0 = *(const uint4*)(xh + (((unsigned)c0) << 6) + (t << 3));
                const uint4 p1 = *(const uint4*)(xh + (((unsigned)c1) << 6) + (t << 3));

                const __half* h0 = (const __half*)&p0;
                const __half* h1 = (const __half*)&p1;
#pragma unroll
                for (int j = 0; j < 8; ++j) a[j] += __half2float(h0[j]) * w0;
#pragma unroll
                for (int j = 0; j < 8; ++j) a[j] += __half2float(h1[j]) * w1;
            }
        }

#define RED(m) a[0]+=__shfl_xor(a[0],m); a[1]+=__shfl_xor(a[1],m); \
               a[2]+=__shfl_xor(a[2],m); a[3]+=__shfl_xor(a[3],m); \
               a[4]+=__shfl_xor(a[4],m); a[5]+=__shfl_xor(a[5],m); \
               a[6]+=__shfl_xor(a[6],m); a[7]+=__shfl_xor(a[7],m);
        RED(8) RED(16) RED(32)
#undef RED

        if (lane < 8) {
            float4 r0v; r0v.x=a[0]; r0v.y=a[1]; r0v.z=a[2]; r0v.w=a[3];
            float4 r1v; r1v.x=a[4]; r1v.y=a[5]; r1v.z=a[6]; r1v.w=a[7];
            float* dst = out + (((size_t)row) << 6) + (t << 3);
            *(float4*)(dst)     = r0v;
            *(float4*)(dst + 4) = r1v;
        }
    }
}

// ---------- unsorted fp16 kernel (fallback if ws fits only xh) ----------
__global__ __launch_bounds__(256) void spmm_half_kernel(
    const __half* __restrict__ xh,
    const int*   __restrict__ indptr,
    const int*   __restrict__ indices,
    const float* __restrict__ values,
    float*       __restrict__ out,
    int n_nodes)
{
    const int row  = (int)((blockIdx.x * blockDim.x + threadIdx.x) >> 6);
    const int lane = (int)(threadIdx.x & 63);
    if (row >= n_nodes) return;
    const int g = lane >> 3;
    const int t = lane & 7;

    const int start = indptr[row];
    const int end   = indptr[row + 1];

    float a[8] = {0.f,0.f,0.f,0.f,0.f,0.f,0.f,0.f};

    if (start < end) {
        const int last = end - 1;
        for (int k = start; k < end; k += 16) {
            const int e0 = k + g;
            const int e1 = k + 8 + g;
            const int i0 = (e0 <= last) ? e0 : last;
            const int i1 = (e1 <= last) ? e1 : last;
            const int c0 = indices[i0];
            const int c1 = indices[i1];
            const float w0 = (e0 <= last) ? values[i0] : 0.0f;
            const float w1 = (e1 <= last) ? values[i1] : 0.0f;
            const uint4 p0 = *(const uint4*)(xh + (((unsigned)c0) << 6) + (t << 3));
            const uint4 p1 = *(const uint4*)(xh + (((unsigned)c1) << 6) + (t << 3));
            const __half* h0 = (const __half*)&p0;
            const __half* h1 = (const __half*)&p1;
#pragma unroll
            for (int j = 0; j < 8; ++j) a[j] += __half2float(h0[j]) * w0;
#pragma unroll
            for (int j = 0; j < 8; ++j) a[j] += __half2float(h1[j]) * w1;
        }
    }

#define RED(m) a[0]+=__shfl_xor(a[0],m); a[1]+=__shfl_xor(a[1],m); \
               a[2]+=__shfl_xor(a[2],m); a[3]+=__shfl_xor(a[3],m); \
               a[4]+=__shfl_xor(a[4],m); a[5]+=__shfl_xor(a[5],m); \
               a[6]+=__shfl_xor(a[6],m); a[7]+=__shfl_xor(a[7],m);
    RED(8) RED(16) RED(32)
#undef RED

    if (lane < 8) {
        float4 r0; r0.x=a[0]; r0.y=a[1]; r0.z=a[2]; r0.w=a[3];
        float4 r1; r1.x=a[4]; r1.y=a[5]; r1.z=a[6]; r1.w=a[7];
        float* dst = out + (((size_t)row) << 6) + (t << 3);
        *(float4*)(dst)     = r0;
        *(float4*)(dst + 4) = r1;
    }
}

// ---------- f32 fallback (ws too small for anything) ----------
__global__ __launch_bounds__(256) void spmm_quad_kernel(
    const float* __restrict__ x,
    const int*   __restrict__ indptr,
    const int*   __restrict__ indices,
    const float* __restrict__ values,
    float*       __restrict__ out,
    int n_nodes)
{
    const int row  = (int)((blockIdx.x * blockDim.x + threadIdx.x) >> 6);
    const int lane = (int)(threadIdx.x & 63);
    if (row >= n_nodes) return;

    const int start = indptr[row];
    const int end   = indptr[row + 1];
    const int g     = lane >> 4;
    const unsigned col4 = (unsigned)(lane & 15) << 2;

    float ax = 0.f, ay = 0.f, az = 0.f, aw = 0.f;

    if (start < end) {
        const int last = end - 1;
        for (int k = start; k < end; k += 16) {
            const int e0 = k + 0 + g, e1 = k + 4 + g, e2 = k + 8 + g, e3 = k + 12 + g;
            const int ce0 = e0 <= last ? e0 : last;
            const int ce1 = e1 <= last ? e1 : last;
            const int ce2 = e2 <= last ? e2 : last;
            const int ce3 = e3 <= last ? e3 : last;
            const int c0 = indices[ce0], c1 = indices[ce1];
            const int c2 = indices[ce2], c3 = indices[ce3];
            const float w0 = (e0 <= last) ? values[ce0] : 0.0f;
            const float w1 = (e1 <= last) ? values[ce1] : 0.0f;
            const float w2 = (e2 <= last) ? values[ce2] : 0.0f;
            const float w3 = (e3 <= last) ? values[ce3] : 0.0f;
            const float4 a0 = *(const float4*)(x + (((unsigned)c0) << 6) + col4);
            const float4 a1 = *(const float4*)(x + (((unsigned)c1) << 6) + col4);
            const float4 a2 = *(const float4*)(x + (((unsigned)c2) << 6) + col4);
            const float4 a3 = *(const float4*)(x + (((unsigned)c3) << 6) + col4);
            ax += w0 * a0.x; ay += w0 * a0.y; az += w0 * a0.z; aw += w0 * a0.w;
            ax += w1 * a1.x; ay += w1 * a1.y; az += w1 * a1.z; aw += w1 * a1.w;
            ax += w2 * a2.x; ay += w2 * a2.y; az += w2 * a2.z; aw += w2 * a2.w;
            ax += w3 * a3.x; ay += w3 * a3.y; az += w3 * a3.z; aw += w3 * a3.w;
        }
    }

    ax += __shfl_xor(ax, 16); ay += __shfl_xor(ay, 16);
    az += __shfl_xor(az, 16); aw += __shfl_xor(aw, 16);
    ax += __shfl_xor(ax, 32); ay += __shfl_xor(ay, 32);
    az += __shfl_xor(az, 32); aw += __shfl_xor(aw, 32);

    if (lane < 16) {
        float4 r; r.x = ax; r.y = ay; r.z = az; r.w = aw;
        *(float4*)(out + ((size_t)row << 6) + col4) = r;
    }
}

extern "C" void kernel_launch(void* const* d_in, const int* in_sizes, int n_in,
                              void* d_out, int out_size, void* d_ws, size_t ws_size,
                              hipStream_t stream) {
    const float* x       = (const float*)d_in[0];
    const int*   indptr  = (const int*)  d_in[1];
    const int*   indices = (const int*)  d_in[2];
    const float* values  = (const float*)d_in[3];
    float*       out     = (float*)d_out;

    const int n_nodes = in_sizes[1] - 1;     // indptr has N+1 entries
    const int n_xelem = in_sizes[0];         // N * 64
    const int n_edges = in_sizes[2];

    const int threads = 256;
    const int row_blocks = (n_nodes + 3) / 4;            // 4 waves/block

    const size_t xh_bytes   = (size_t)n_xelem * sizeof(__half);
    const size_t sort_bytes = (size_t)n_edges * (sizeof(int) + sizeof(float));

    if (ws_size >= xh_bytes + sort_bytes) {
        __half* xh   = (__half*)d_ws;
        int*    sidx = (int*)((char*)d_ws + xh_bytes);
        float*  sval = (float*)((char*)sidx + (size_t)n_edges * sizeof(int));

        cvt_half_kernel<<<2048, threads, 0, stream>>>(x, xh, n_xelem / 4);
        sort_rows_kernel<<<row_blocks, threads, 0, stream>>>(
            indptr, indices, values, sidx, sval, n_nodes);

        const int blocks  = 2048;                        // fully co-resident
        const int n_waves = blocks * (threads / 64);
        spmm_half_sorted_kernel<<<blocks, threads, 0, stream>>>(
            xh, indptr, sidx, sval, out, n_nodes, n_edges, n_waves);
    } else if (ws_size >= xh_bytes) {
        __half* xh = (__half*)d_ws;
        cvt_half_kernel<<<2048, threads, 0, stream>>>(x, xh, n_xelem / 4);
        spmm_half_kernel<<<row_blocks, threads, 0, stream>>>(
            xh, indptr, indices, values, out, n_nodes);
    } else {
        spmm_quad_kernel<<<row_blocks, threads, 0, stream>>>(
            x, indptr, indices, values, out, n_nodes);
    }
}

// Round 10
// 74.970 us; speedup vs baseline: 1.2518x; 1.2518x over previous
//
#include <hip/hip_runtime.h>
#include <hip/hip_fp16.h>

#define DIM 64

// ---------- pass 1: compress x (f32) -> xh (fp16) in workspace ----------
__global__ __launch_bounds__(256) void cvt_half_kernel(
    const float* __restrict__ x, __half* __restrict__ xh, int n4)
{
    int i = blockIdx.x * blockDim.x + threadIdx.x;
    const int stride = gridDim.x * blockDim.x;
    for (; i < n4; i += stride) {
        const float4 v = ((const float4*)x)[i];
        __half2 h0 = __floats2half2_rn(v.x, v.y);
        __half2 h1 = __floats2half2_rn(v.z, v.w);
        uint2 u;
        u.x = *(const unsigned int*)&h0;
        u.y = *(const unsigned int*)&h1;
        ((uint2*)xh)[i] = u;
    }
}

// load first-tile (16-edge) idx/val of a row with extents [S,E); clamped+safe
#define LOAD_TILE_IDX(S, E, C0, C1, W0, W1)                                    \
    {                                                                          \
        const int last_ = (E) - 1;                                             \
        const int e0_ = (S) + g, e1_ = (S) + 8 + g;                            \
        int i0_ = e0_ <= last_ ? e0_ : last_; if (i0_ < 0) i0_ = 0;            \
        int i1_ = e1_ <= last_ ? e1_ : last_; if (i1_ < 0) i1_ = 0;            \
        C0 = indices[i0_];                                                     \
        C1 = indices[i1_];                                                     \
        W0 = (e0_ <= last_) ? values[i0_] : 0.0f;                              \
        W1 = (e1_ <= last_) ? values[i1_] : 0.0f;                              \
    }

#define GATHER(C0, C1, P0, P1)                                                 \
    {                                                                          \
        P0 = *(const uint4*)(xh + (((unsigned)(C0)) << 6) + (t << 3));         \
        P1 = *(const uint4*)(xh + (((unsigned)(C1)) << 6) + (t << 3));         \
    }

#define FMA8(P, W)                                                             \
    {                                                                          \
        const __half* h_ = (const __half*)&(P);                                \
        _Pragma("unroll")                                                      \
        for (int j = 0; j < 8; ++j) a[j] += __half2float(h_[j]) * (W);         \
    }

// ---------- pass 2: CSR SpMM, balanced row ranges, 3-deep row pipeline -----
// Wave w handles rows [lb(E*w/W), lb(E*(w+1)/W)). Per iteration (row r):
//   prefetch extents(r+3); issue gathers(r+1); load idx/val(r+2);
//   FMA r's in-flight gathers; drain r's >16-edge tail; reduce+store r.
// Keeps a gather-pair (16 cache lines) in flight per wave at all times.
__global__ __launch_bounds__(256) void spmm_half_pipe_kernel(
    const __half* __restrict__ xh,
    const int*   __restrict__ indptr,
    const int*   __restrict__ indices,
    const float* __restrict__ values,
    float*       __restrict__ out,
    int n_nodes, int n_edges, int n_waves)
{
    const int wave = (int)((blockIdx.x * blockDim.x + threadIdx.x) >> 6);
    const int lane = (int)(threadIdx.x & 63);
    if (wave >= n_waves) return;
    const int g = lane >> 3;        // edge slot 0..7
    const int t = lane & 7;         // column octet

    // balanced row range: first row with indptr[r] >= target
    const long long T0 = (long long)n_edges * wave / n_waves;
    const long long T1 = (long long)n_edges * (wave + 1) / n_waves;
    int lo = 0, hi = n_nodes;
    while (lo < hi) { int mid = (lo + hi) >> 1; if ((long long)indptr[mid] < T0) lo = mid + 1; else hi = mid; }
    const int r0 = lo;
    int r1;
    if (wave == n_waves - 1) { r1 = n_nodes; }
    else {
        lo = r0; hi = n_nodes;
        while (lo < hi) { int mid = (lo + hi) >> 1; if ((long long)indptr[mid] < T1) lo = mid + 1; else hi = mid; }
        r1 = lo;
    }
    if (r0 >= r1) return;
    const int rmax = r1 - 1;

    // ---- pipeline prologue ----
    const int rB = (r0 + 1 <= rmax) ? r0 + 1 : rmax;
    const int rX = (r0 + 2 <= rmax) ? r0 + 2 : rmax;
    int sC = indptr[r0];  int eC = indptr[r0 + 1];
    int sN = indptr[rB];  int eN = indptr[rB + 1];
    int s2 = indptr[rX];  int e2 = indptr[rX + 1];

    int   cA0, cA1, cB0, cB1;
    float wA0, wA1, wB0, wB1;
    LOAD_TILE_IDX(sC, eC, cA0, cA1, wA0, wA1)
    LOAD_TILE_IDX(sN, eN, cB0, cB1, wB0, wB1)
    uint4 pA0, pA1;
    GATHER(cA0, cA1, pA0, pA1)

    for (int rC = r0; rC < r1; ++rC) {
        // 1. prefetch extents of row rC+3
        int r3 = rC + 3; if (r3 > rmax) r3 = rmax;
        const int s3 = indptr[r3];
        const int e3 = indptr[r3 + 1];

        // 2. issue gathers for row rC+1 (idx arrived one iteration ago)
        uint4 pB0, pB1;
        GATHER(cB0, cB1, pB0, pB1)

        // 3. load idx/val for row rC+2 (extents arrived one iteration ago)
        int cC0, cC1; float wC0, wC1;
        LOAD_TILE_IDX(s2, e2, cC0, cC1, wC0, wC1)

        // 4. FMA row rC's first tile (gathers issued one iteration ago)
        float a[8] = {0.f,0.f,0.f,0.f,0.f,0.f,0.f,0.f};
        FMA8(pA0, wA0)
        FMA8(pA1, wA1)

        // 5. drain extra tiles of long rows (serial; ~38% of rows)
        {
            const int last_ = eC - 1;
            for (int k = sC + 16; k < eC; k += 16) {
                const int e0_ = k + g, e1_ = k + 8 + g;
                const int i0_ = e0_ <= last_ ? e0_ : last_;
                const int i1_ = e1_ <= last_ ? e1_ : last_;
                const int c0_ = indices[i0_];
                const int c1_ = indices[i1_];
                const float w0_ = (e0_ <= last_) ? values[i0_] : 0.0f;
                const float w1_ = (e1_ <= last_) ? values[i1_] : 0.0f;
                uint4 q0, q1;
                GATHER(c0_, c1_, q0, q1)
                FMA8(q0, w0_)
                FMA8(q1, w1_)
            }
        }

        // 6. reduce across the 8 edge slots and store row rC
#define RED(m) a[0]+=__shfl_xor(a[0],m); a[1]+=__shfl_xor(a[1],m); \
               a[2]+=__shfl_xor(a[2],m); a[3]+=__shfl_xor(a[3],m); \
               a[4]+=__shfl_xor(a[4],m); a[5]+=__shfl_xor(a[5],m); \
               a[6]+=__shfl_xor(a[6],m); a[7]+=__shfl_xor(a[7],m);
        RED(8) RED(16) RED(32)
#undef RED
        if (lane < 8) {
            float4 v0; v0.x=a[0]; v0.y=a[1]; v0.z=a[2]; v0.w=a[3];
            float4 v1; v1.x=a[4]; v1.y=a[5]; v1.z=a[6]; v1.w=a[7];
            float* dst = out + (((size_t)rC) << 6) + (t << 3);
            *(float4*)(dst)     = v0;
            *(float4*)(dst + 4) = v1;
        }

        // 7. rotate pipeline registers
        sC = sN; eC = eN; sN = s2; eN = e2; s2 = s3; e2 = e3;
        cA0 = cB0; cA1 = cB1; wA0 = wB0; wA1 = wB1;
        pA0 = pB0; pA1 = pB1;
        cB0 = cC0; cB1 = cC1; wB0 = wC0; wB1 = wC1;
    }
}

// ---------- unsorted fp16 kernel (fallback / reference structure) ----------
__global__ __launch_bounds__(256) void spmm_half_kernel(
    const __half* __restrict__ xh,
    const int*   __restrict__ indptr,
    const int*   __restrict__ indices,
    const float* __restrict__ values,
    float*       __restrict__ out,
    int n_nodes)
{
    const int row  = (int)((blockIdx.x * blockDim.x + threadIdx.x) >> 6);
    const int lane = (int)(threadIdx.x & 63);
    if (row >= n_nodes) return;
    const int g = lane >> 3;
    const int t = lane & 7;

    const int start = indptr[row];
    const int end   = indptr[row + 1];

    float a[8] = {0.f,0.f,0.f,0.f,0.f,0.f,0.f,0.f};

    if (start < end) {
        const int last = end - 1;
        for (int k = start; k < end; k += 16) {
            const int e0 = k + g;
            const int e1 = k + 8 + g;
            const int i0 = (e0 <= last) ? e0 : last;
            const int i1 = (e1 <= last) ? e1 : last;
            const int c0 = indices[i0];
            const int c1 = indices[i1];
            const float w0 = (e0 <= last) ? values[i0] : 0.0f;
            const float w1 = (e1 <= last) ? values[i1] : 0.0f;
            const uint4 p0 = *(const uint4*)(xh + (((unsigned)c0) << 6) + (t << 3));
            const uint4 p1 = *(const uint4*)(xh + (((unsigned)c1) << 6) + (t << 3));
            FMA8(p0, w0)
            FMA8(p1, w1)
        }
    }

#define RED(m) a[0]+=__shfl_xor(a[0],m); a[1]+=__shfl_xor(a[1],m); \
               a[2]+=__shfl_xor(a[2],m); a[3]+=__shfl_xor(a[3],m); \
               a[4]+=__shfl_xor(a[4],m); a[5]+=__shfl_xor(a[5],m); \
               a[6]+=__shfl_xor(a[6],m); a[7]+=__shfl_xor(a[7],m);
    RED(8) RED(16) RED(32)
#undef RED

    if (lane < 8) {
        float4 r0; r0.x=a[0]; r0.y=a[1]; r0.z=a[2]; r0.w=a[3];
        float4 r1; r1.x=a[4]; r1.y=a[5]; r1.z=a[6]; r1.w=a[7];
        float* dst = out + (((size_t)row) << 6) + (t << 3);
        *(float4*)(dst)     = r0;
        *(float4*)(dst + 4) = r1;
    }
}

// ---------- f32 fallback (ws too small) ----------
__global__ __launch_bounds__(256) void spmm_quad_kernel(
    const float* __restrict__ x,
    const int*   __restrict__ indptr,
    const int*   __restrict__ indices,
    const float* __restrict__ values,
    float*       __restrict__ out,
    int n_nodes)
{
    const int row  = (int)((blockIdx.x * blockDim.x + threadIdx.x) >> 6);
    const int lane = (int)(threadIdx.x & 63);
    if (row >= n_nodes) return;

    const int start = indptr[row];
    const int end   = indptr[row + 1];
    const int g     = lane >> 4;
    const unsigned col4 = (unsigned)(lane & 15) << 2;

    float ax = 0.f, ay = 0.f, az = 0.f, aw = 0.f;

    if (start < end) {
        const int last = end - 1;
        for (int k = start; k < end; k += 16) {
            const int e0 = k + 0 + g, e1 = k + 4 + g, e2 = k + 8 + g, e3 = k + 12 + g;
            const int ce0 = e0 <= last ? e0 : last;
            const int ce1 = e1 <= last ? e1 : last;
            const int ce2 = e2 <= last ? e2 : last;
            const int ce3 = e3 <= last ? e3 : last;
            const int c0 = indices[ce0], c1 = indices[ce1];
            const int c2 = indices[ce2], c3 = indices[ce3];
            const float w0 = (e0 <= last) ? values[ce0] : 0.0f;
            const float w1 = (e1 <= last) ? values[ce1] : 0.0f;
            const float w2 = (e2 <= last) ? values[ce2] : 0.0f;
            const float w3 = (e3 <= last) ? values[ce3] : 0.0f;
            const float4 a0 = *(const float4*)(x + (((unsigned)c0) << 6) + col4);
            const float4 a1 = *(const float4*)(x + (((unsigned)c1) << 6) + col4);
            const float4 a2 = *(const float4*)(x + (((unsigned)c2) << 6) + col4);
            const float4 a3 = *(const float4*)(x + (((unsigned)c3) << 6) + col4);
            ax += w0 * a0.x; ay += w0 * a0.y; az += w0 * a0.z; aw += w0 * a0.w;
            ax += w1 * a1.x; ay += w1 * a1.y; az += w1 * a1.z; aw += w1 * a1.w;
            ax += w2 * a2.x; ay += w2 * a2.y; az += w2 * a2.z; aw += w2 * a2.w;
            ax += w3 * a3.x; ay += w3 * a3.y; az += w3 * a3.z; aw += w3 * a3.w;
        }
    }

    ax += __shfl_xor(ax, 16); ay += __shfl_xor(ay, 16);
    az += __shfl_xor(az, 16); aw += __shfl_xor(aw, 16);
    ax += __shfl_xor(ax, 32); ay += __shfl_xor(ay, 32);
    az += __shfl_xor(az, 32); aw += __shfl_xor(aw, 32);

    if (lane < 16) {
        float4 r; r.x = ax; r.y = ay; r.z = az; r.w = aw;
        *(float4*)(out + ((size_t)row << 6) + col4) = r;
    }
}

extern "C" void kernel_launch(void* const* d_in, const int* in_sizes, int n_in,
                              void* d_out, int out_size, void* d_ws, size_t ws_size,
                              hipStream_t stream) {
    const float* x       = (const float*)d_in[0];
    const int*   indptr  = (const int*)  d_in[1];
    const int*   indices = (const int*)  d_in[2];
    const float* values  = (const float*)d_in[3];
    float*       out     = (float*)d_out;

    const int n_nodes = in_sizes[1] - 1;     // indptr has N+1 entries
    const int n_xelem = in_sizes[0];         // N * 64
    const int n_edges = in_sizes[2];

    const int threads = 256;

    const size_t xh_bytes = (size_t)n_xelem * sizeof(__half);
    if (ws_size >= xh_bytes) {
        __half* xh = (__half*)d_ws;
        cvt_half_kernel<<<2048, threads, 0, stream>>>(x, xh, n_xelem / 4);

        const int blocks  = 2048;            // co-resident
        const int n_waves = blocks * (threads / 64);
        spmm_half_pipe_kernel<<<blocks, threads, 0, stream>>>(
            xh, indptr, indices, values, out, n_nodes, n_edges, n_waves);
    } else {
        const int row_blocks = (n_nodes + 3) / 4;
        spmm_quad_kernel<<<row_blocks, threads, 0, stream>>>(
            x, indptr, indices, values, out, n_nodes);
    }
}